// Round 4
// baseline (347.757 us; speedup 1.0000x reference)
//
#include <hip/hip_runtime.h>
#include <hip/hip_bf16.h>

typedef __bf16 bf16;
typedef __bf16 bf16x8 __attribute__((ext_vector_type(8)));
typedef __bf16 bf16x4 __attribute__((ext_vector_type(4)));
typedef float f32x4 __attribute__((ext_vector_type(4)));

#define B_   4
#define T_   2048
#define DM_  1024
#define DH_  1024
#define MROWS 8192

// ---------------------------------------------------------------------------
// fp32 -> bf16, 32 elems/thread: 8 independent dwordx4 loads in flight,
// 4 bf16x8 stores. Block covers 8192 floats (2048 float4). Jobs sized in
// float4 units; oversized grid blocks exit early (uniform per block).
// ---------------------------------------------------------------------------
struct CvtJob { const float* src; bf16* dst; int nf4; };
struct CvtArgs { CvtJob job[7]; };

__global__ __launch_bounds__(256) void cvt_kernel(CvtArgs args) {
  CvtJob jb = args.job[blockIdx.y];
  int base = blockIdx.x * 2048;
  if (base >= jb.nf4) return;
  int t2 = threadIdx.x * 2;
  const float4* s = (const float4*)jb.src;
  float4 a[4][2];
#pragma unroll
  for (int u = 0; u < 4; ++u) {
    a[u][0] = s[base + u * 512 + t2];
    a[u][1] = s[base + u * 512 + t2 + 1];
  }
#pragma unroll
  for (int u = 0; u < 4; ++u) {
    bf16x8 o;
    o[0] = (bf16)a[u][0].x; o[1] = (bf16)a[u][0].y;
    o[2] = (bf16)a[u][0].z; o[3] = (bf16)a[u][0].w;
    o[4] = (bf16)a[u][1].x; o[5] = (bf16)a[u][1].y;
    o[6] = (bf16)a[u][1].z; o[7] = (bf16)a[u][1].w;
    *(bf16x8*)(jb.dst + ((size_t)base + u * 512 + t2) * 4) = o;
  }
}

// ---------------------------------------------------------------------------
// C[M,N] = A[M,K] * B[N,K]^T, all-bf16 operands. m97 structure: 128x128
// tile, BK=64, 4 waves 2x2, 4x4 MFMA 16x16x32, global_load_lds width=16,
// XOR-swizzled LDS (0 bank conflicts, verified r2). Async staging is load-
// bearing: r3's sync load->cvt->ds_write variant cost +40% (latency on the
// K-loop critical path) — do not fuse fp32 conversion here.
// Epilogue mode: 0 = fp32 store; 1 = bf16(sigmoid(acc)); 2 = bf16(acc).
// XCD swizzle (needs gridDim.x==8, gridDim.y%8==0): blocks sharing tileM
// land on one XCD (id%8 round-robin) so A rows are fetched ~once per XCD.
// ---------------------------------------------------------------------------
struct GemmJob { const bf16* A; const bf16* Bw; float* Cf; bf16* Cb; int mode; };
struct GemmArgs { GemmJob job[4]; int N; int K; };

__global__ __launch_bounds__(256) void gemm_bt(GemmArgs ga) {
  const GemmJob jb = ga.job[blockIdx.z];
  const int N = ga.N, K = ga.K;
  __shared__ bf16 As[128 * 64];
  __shared__ bf16 Bs[128 * 64];

  const int tid  = threadIdx.x;
  const int lane = tid & 63;
  const int wave = tid >> 6;
  const int wm   = (wave >> 1) * 64;
  const int wn   = (wave & 1) * 64;

  const int f   = blockIdx.y * 8 + blockIdx.x;
  const int xcd = f & 7;
  const int j   = f >> 3;
  const int bn  = j & 7;
  const int bm  = (j >> 3) * 8 + xcd;
  const int tileM = bm * 128;
  const int tileN = bn * 128;

  f32x4 acc[4][4] = {};

  const int sr = lane >> 3;             // row within 8-row group
  const int sc = (lane & 7) ^ sr;       // swizzled source k-chunk

  for (int k0 = 0; k0 < K; k0 += 64) {
#pragma unroll
    for (int l = 0; l < 4; ++l) {
      int grp = wave * 4 + l;
      int row = grp * 8 + sr;
      const bf16* gaadr = jb.A + (size_t)(tileM + row) * K + k0 + sc * 8;
      __builtin_amdgcn_global_load_lds(
          (const __attribute__((address_space(1))) void*)gaadr,
          (__attribute__((address_space(3))) void*)&As[grp * 512], 16, 0, 0);
      const bf16* gbadr = jb.Bw + (size_t)(tileN + row) * K + k0 + sc * 8;
      __builtin_amdgcn_global_load_lds(
          (const __attribute__((address_space(1))) void*)gbadr,
          (__attribute__((address_space(3))) void*)&Bs[grp * 512], 16, 0, 0);
    }
    __syncthreads();

    const int quad = lane >> 4;
#pragma unroll
    for (int s = 0; s < 2; ++s) {
      bf16x8 af[4], bfr[4];
#pragma unroll
      for (int mt = 0; mt < 4; ++mt) {
        int row = wm + mt * 16 + (lane & 15);
        int chunk = (s * 4 + quad) ^ (row & 7);
        af[mt] = *(const bf16x8*)&As[row * 64 + chunk * 8];
      }
#pragma unroll
      for (int nt = 0; nt < 4; ++nt) {
        int row = wn + nt * 16 + (lane & 15);
        int chunk = (s * 4 + quad) ^ (row & 7);
        bfr[nt] = *(const bf16x8*)&Bs[row * 64 + chunk * 8];
      }
#pragma unroll
      for (int mt = 0; mt < 4; ++mt)
#pragma unroll
        for (int nt = 0; nt < 4; ++nt)
          acc[mt][nt] = __builtin_amdgcn_mfma_f32_16x16x32_bf16(
              af[mt], bfr[nt], acc[mt][nt], 0, 0, 0);
    }
    __syncthreads();
  }

  // epilogue: C/D layout col=lane&15, row=(lane>>4)*4+reg
  const int cn = lane & 15;
  const int cr = (lane >> 4) * 4;
  if (jb.mode == 0) {
#pragma unroll
    for (int mt = 0; mt < 4; ++mt)
#pragma unroll
      for (int nt = 0; nt < 4; ++nt)
#pragma unroll
        for (int r = 0; r < 4; ++r) {
          int row = tileM + wm + mt * 16 + cr + r;
          int col = tileN + wn + nt * 16 + cn;
          jb.Cf[(size_t)row * N + col] = acc[mt][nt][r];
        }
  } else if (jb.mode == 1) {
#pragma unroll
    for (int mt = 0; mt < 4; ++mt)
#pragma unroll
      for (int nt = 0; nt < 4; ++nt)
#pragma unroll
        for (int r = 0; r < 4; ++r) {
          int row = tileM + wm + mt * 16 + cr + r;
          int col = tileN + wn + nt * 16 + cn;
          jb.Cb[(size_t)row * N + col] =
              (bf16)(1.f / (1.f + __expf(-acc[mt][nt][r])));
        }
  } else {
#pragma unroll
    for (int mt = 0; mt < 4; ++mt)
#pragma unroll
      for (int nt = 0; nt < 4; ++nt)
#pragma unroll
        for (int r = 0; r < 4; ++r) {
          int row = tileM + wm + mt * 16 + cr + r;
          int col = tileN + wn + nt * 16 + cn;
          jb.Cb[(size_t)row * N + col] = (bf16)acc[mt][nt][r];
        }
  }
}

// ---------------------------------------------------------------------------
// ratio reduction over bf16 K/V: m[j,d]=max_b K; w=exp(K-m);
// num[b,d]+=w*V; den[b,d]+=w.  Thread = 8 consecutive d (bf16x8 loads);
// block covers all 1024 d x 32 j (two 16-j halves); 64 j-split blocks.
// ---------------------------------------------------------------------------
__global__ __launch_bounds__(256) void reduce_kv(
    const bf16* __restrict__ Kb, const bf16* __restrict__ Vb,
    float* __restrict__ num, float* __restrict__ den) {
  const int d  = (threadIdx.x & 127) * 8;
  const int j0 = blockIdx.x * 32 + (threadIdx.x >> 7) * 16;
  const size_t bs = (size_t)T_ * DH_;
  float n[4][8] = {}, e[4][8] = {};
  for (int jj = j0; jj < j0 + 16; ++jj) {
    size_t off = (size_t)jj * DH_ + d;
    float kf[4][8], vf[4][8];
#pragma unroll
    for (int b = 0; b < 4; ++b) {
      bf16x8 kk = *(const bf16x8*)(Kb + off + b * bs);
      bf16x8 vv = *(const bf16x8*)(Vb + off + b * bs);
#pragma unroll
      for (int c = 0; c < 8; ++c) { kf[b][c] = (float)kk[c]; vf[b][c] = (float)vv[c]; }
    }
#pragma unroll
    for (int c = 0; c < 8; ++c) {
      float m = fmaxf(fmaxf(kf[0][c], kf[1][c]), fmaxf(kf[2][c], kf[3][c]));
#pragma unroll
      for (int b = 0; b < 4; ++b) {
        float w = __expf(kf[b][c] - m);
        e[b][c] += w;
        n[b][c] += w * vf[b][c];
      }
    }
  }
#pragma unroll
  for (int b = 0; b < 4; ++b)
#pragma unroll
    for (int c = 0; c < 8; ++c) {
      atomicAdd(&num[b * DH_ + d + c], n[b][c]);
      atomicAdd(&den[b * DH_ + d + c], e[b][c]);
    }
}

// ---------------------------------------------------------------------------
// Yb[i] *= num[b,h]/den[b,h]  (in place, bf16) — folds the ratio into the
// out-GEMM's A operand so one GEMM with a single 2 MB B covers all batches.
// ---------------------------------------------------------------------------
__global__ __launch_bounds__(256) void mul_ratio(
    bf16* __restrict__ Yb, const float* __restrict__ num,
    const float* __restrict__ den) {
  size_t i = ((size_t)blockIdx.x * 256 + threadIdx.x) * 8;
  int h = (int)(i & (DH_ - 1));
  int b = (int)(i >> 21);                 // i / (T_*DH_), 2^21
  bf16x8 y = *(bf16x8*)(Yb + i);
  const float* nu = num + b * DH_ + h;
  const float* de = den + b * DH_ + h;
  float4 n0 = *(const float4*)nu;
  float4 n1 = *(const float4*)(nu + 4);
  float4 d0 = *(const float4*)de;
  float4 d1 = *(const float4*)(de + 4);
  bf16x8 o;
  o[0] = (bf16)((float)y[0] * n0.x / d0.x);
  o[1] = (bf16)((float)y[1] * n0.y / d0.y);
  o[2] = (bf16)((float)y[2] * n0.z / d0.z);
  o[3] = (bf16)((float)y[3] * n0.w / d0.w);
  o[4] = (bf16)((float)y[4] * n1.x / d1.x);
  o[5] = (bf16)((float)y[5] * n1.y / d1.y);
  o[6] = (bf16)((float)y[6] * n1.z / d1.z);
  o[7] = (bf16)((float)y[7] * n1.w / d1.w);
  *(bf16x8*)(Yb + i) = o;
}

// ---------------------------------------------------------------------------
extern "C" void kernel_launch(void* const* d_in, const int* in_sizes, int n_in,
                              void* d_out, int out_size, void* d_ws, size_t ws_size,
                              hipStream_t stream) {
  const float* q  = (const float*)d_in[0];
  const float* k  = (const float*)d_in[1];
  const float* v  = (const float*)d_in[2];
  const float* Wq = (const float*)d_in[3];
  const float* Wk = (const float*)d_in[4];
  const float* Wv = (const float*)d_in[5];
  const float* Wo = (const float*)d_in[6];
  // d_in[7] = W_bias mathematically unused (exp_pos_bias == all-ones).
  float* out = (float*)d_out;

  char* ws = (char*)d_ws;
  size_t off = 0;
  auto alloc = [&](size_t bytes) {
    char* p = ws + off;
    off += (bytes + 255) & ~(size_t)255;
    return p;
  };
  const size_t actN = (size_t)MROWS * DM_;   // 8388608
  const size_t wN   = (size_t)DH_ * DM_;     // 1048576

  bf16* qb  = (bf16*)alloc(actN * 2);
  bf16* kb  = (bf16*)alloc(actN * 2);
  bf16* vb  = (bf16*)alloc(actN * 2);
  bf16* Wqb = (bf16*)alloc(wN * 2);
  bf16* Wkb = (bf16*)alloc(wN * 2);
  bf16* Wvb = (bf16*)alloc(wN * 2);
  bf16* Wob = (bf16*)alloc(wN * 2);
  bf16* Kb  = (bf16*)alloc(actN * 2);
  bf16* Vb  = (bf16*)alloc(actN * 2);
  bf16* Yb  = (bf16*)alloc(actN * 2);
  float* num = (float*)alloc(B_ * DH_ * 4);
  float* den = (float*)alloc(B_ * DH_ * 4);

  // 1) fp32 -> bf16 (activations + all 4 weights)
  CvtArgs ca;
  ca.job[0] = {q,  qb,  (int)(actN / 4)};
  ca.job[1] = {k,  kb,  (int)(actN / 4)};
  ca.job[2] = {v,  vb,  (int)(actN / 4)};
  ca.job[3] = {Wq, Wqb, (int)(wN / 4)};
  ca.job[4] = {Wk, Wkb, (int)(wN / 4)};
  ca.job[5] = {Wv, Wvb, (int)(wN / 4)};
  ca.job[6] = {Wo, Wob, (int)(wN / 4)};
  cvt_kernel<<<dim3(actN / 4 / 2048, 7), 256, 0, stream>>>(ca);

  hipMemsetAsync(num, 0, 2 * B_ * DH_ * sizeof(float), stream);

  // 2) merged K/V/Q projections (async bf16 staging; Q epilogue = sigmoid)
  GemmArgs g1;
  g1.N = DH_; g1.K = DM_;
  g1.job[0] = {kb, Wkb, nullptr, Kb, 2};
  g1.job[1] = {vb, Wvb, nullptr, Vb, 2};
  g1.job[2] = {qb, Wqb, nullptr, Yb, 1};
  g1.job[3] = {nullptr, nullptr, nullptr, nullptr, 0};
  gemm_bt<<<dim3(8, MROWS / 128, 3), 256, 0, stream>>>(g1);

  // 3) batch-max + exp + sums
  reduce_kv<<<dim3(64), 256, 0, stream>>>(Kb, Vb, num, den);

  // 4) fold ratio into Y (in place)
  mul_ratio<<<dim3(actN / 8 / 256), 256, 0, stream>>>(Yb, num, den);

  // 5) out = Y' @ Wo^T  (single job, B shared across batches)
  GemmArgs g2;
  g2.N = DM_; g2.K = DH_;
  g2.job[0] = {Yb, Wob, out, nullptr, 0};
  g2.job[1] = g2.job[2] = g2.job[3] = {nullptr, nullptr, nullptr, nullptr, 0};
  gemm_bt<<<dim3(8, MROWS / 128, 1), 256, 0, stream>>>(g2);
}

// Round 5
// 279.104 us; speedup vs baseline: 1.2460x; 1.2460x over previous
//
#include <hip/hip_runtime.h>
#include <hip/hip_bf16.h>

typedef __bf16 bf16;
typedef __bf16 bf16x8 __attribute__((ext_vector_type(8)));
typedef __bf16 bf16x4 __attribute__((ext_vector_type(4)));
typedef float f32x4 __attribute__((ext_vector_type(4)));

#define B_   4
#define T_   2048
#define DM_  1024
#define DH_  1024
#define MROWS 8192

// ---------------------------------------------------------------------------
// fp32 -> bf16, 32 elems/thread: 8 independent dwordx4 loads in flight,
// 4 bf16x8 stores. Block covers 8192 floats (2048 float4).
// ---------------------------------------------------------------------------
struct CvtJob { const float* src; bf16* dst; int nf4; };
struct CvtArgs { CvtJob job[7]; };

__global__ __launch_bounds__(256) void cvt_kernel(CvtArgs args) {
  CvtJob jb = args.job[blockIdx.y];
  int base = blockIdx.x * 2048;
  if (base >= jb.nf4) return;
  int t2 = threadIdx.x * 2;
  const float4* s = (const float4*)jb.src;
  float4 a[4][2];
#pragma unroll
  for (int u = 0; u < 4; ++u) {
    a[u][0] = s[base + u * 512 + t2];
    a[u][1] = s[base + u * 512 + t2 + 1];
  }
#pragma unroll
  for (int u = 0; u < 4; ++u) {
    bf16x8 o;
    o[0] = (bf16)a[u][0].x; o[1] = (bf16)a[u][0].y;
    o[2] = (bf16)a[u][0].z; o[3] = (bf16)a[u][0].w;
    o[4] = (bf16)a[u][1].x; o[5] = (bf16)a[u][1].y;
    o[6] = (bf16)a[u][1].z; o[7] = (bf16)a[u][1].w;
    *(bf16x8*)(jb.dst + ((size_t)base + u * 512 + t2) * 4) = o;
  }
}

// ---------------------------------------------------------------------------
// C[M,N] = A[M,K] * B[N,K]^T, all-bf16. m97 structure: 128x128 tile, BK=64,
// 4 waves 2x2, 4x4 MFMA 16x16x32, global_load_lds w=16, XOR-swizzled LDS
// (0 bank conflicts). Async staging is load-bearing: r3's sync
// load->cvt->ds_write cost +40% — do not fuse fp32 conversion here.
// Epilogue mode: 0 = fp32; 1 = bf16(sigmoid(acc)); 2 = bf16(acc).
// XCD swizzle (gridDim.x==8, gridDim.y%8==0): blocks sharing tileM land on
// one XCD so A rows are fetched ~once per XCD.
// ---------------------------------------------------------------------------
struct GemmJob { const bf16* A; const bf16* Bw; float* Cf; bf16* Cb; int mode; };
struct GemmArgs { GemmJob job[4]; int N; int K; };

__global__ __launch_bounds__(256) void gemm_bt(GemmArgs ga) {
  const GemmJob jb = ga.job[blockIdx.z];
  const int N = ga.N, K = ga.K;
  __shared__ bf16 As[128 * 64];
  __shared__ bf16 Bs[128 * 64];

  const int tid  = threadIdx.x;
  const int lane = tid & 63;
  const int wave = tid >> 6;
  const int wm   = (wave >> 1) * 64;
  const int wn   = (wave & 1) * 64;

  const int f   = blockIdx.y * 8 + blockIdx.x;
  const int xcd = f & 7;
  const int j   = f >> 3;
  const int bn  = j & 7;
  const int bm  = (j >> 3) * 8 + xcd;
  const int tileM = bm * 128;
  const int tileN = bn * 128;

  f32x4 acc[4][4] = {};

  const int sr = lane >> 3;
  const int sc = (lane & 7) ^ sr;

  for (int k0 = 0; k0 < K; k0 += 64) {
#pragma unroll
    for (int l = 0; l < 4; ++l) {
      int grp = wave * 4 + l;
      int row = grp * 8 + sr;
      const bf16* gaadr = jb.A + (size_t)(tileM + row) * K + k0 + sc * 8;
      __builtin_amdgcn_global_load_lds(
          (const __attribute__((address_space(1))) void*)gaadr,
          (__attribute__((address_space(3))) void*)&As[grp * 512], 16, 0, 0);
      const bf16* gbadr = jb.Bw + (size_t)(tileN + row) * K + k0 + sc * 8;
      __builtin_amdgcn_global_load_lds(
          (const __attribute__((address_space(1))) void*)gbadr,
          (__attribute__((address_space(3))) void*)&Bs[grp * 512], 16, 0, 0);
    }
    __syncthreads();

    const int quad = lane >> 4;
#pragma unroll
    for (int s = 0; s < 2; ++s) {
      bf16x8 af[4], bfr[4];
#pragma unroll
      for (int mt = 0; mt < 4; ++mt) {
        int row = wm + mt * 16 + (lane & 15);
        int chunk = (s * 4 + quad) ^ (row & 7);
        af[mt] = *(const bf16x8*)&As[row * 64 + chunk * 8];
      }
#pragma unroll
      for (int nt = 0; nt < 4; ++nt) {
        int row = wn + nt * 16 + (lane & 15);
        int chunk = (s * 4 + quad) ^ (row & 7);
        bfr[nt] = *(const bf16x8*)&Bs[row * 64 + chunk * 8];
      }
#pragma unroll
      for (int mt = 0; mt < 4; ++mt)
#pragma unroll
        for (int nt = 0; nt < 4; ++nt)
          acc[mt][nt] = __builtin_amdgcn_mfma_f32_16x16x32_bf16(
              af[mt], bfr[nt], acc[mt][nt], 0, 0, 0);
    }
    __syncthreads();
  }

  const int cn = lane & 15;
  const int cr = (lane >> 4) * 4;
  if (jb.mode == 0) {
#pragma unroll
    for (int mt = 0; mt < 4; ++mt)
#pragma unroll
      for (int nt = 0; nt < 4; ++nt)
#pragma unroll
        for (int r = 0; r < 4; ++r) {
          int row = tileM + wm + mt * 16 + cr + r;
          int col = tileN + wn + nt * 16 + cn;
          jb.Cf[(size_t)row * N + col] = acc[mt][nt][r];
        }
  } else if (jb.mode == 1) {
#pragma unroll
    for (int mt = 0; mt < 4; ++mt)
#pragma unroll
      for (int nt = 0; nt < 4; ++nt)
#pragma unroll
        for (int r = 0; r < 4; ++r) {
          int row = tileM + wm + mt * 16 + cr + r;
          int col = tileN + wn + nt * 16 + cn;
          jb.Cb[(size_t)row * N + col] =
              (bf16)(1.f / (1.f + __expf(-acc[mt][nt][r])));
        }
  } else {
#pragma unroll
    for (int mt = 0; mt < 4; ++mt)
#pragma unroll
      for (int nt = 0; nt < 4; ++nt)
#pragma unroll
        for (int r = 0; r < 4; ++r) {
          int row = tileM + wm + mt * 16 + cr + r;
          int col = tileN + wn + nt * 16 + cn;
          jb.Cb[(size_t)row * N + col] = (bf16)acc[mt][nt][r];
        }
  }
}

// ---------------------------------------------------------------------------
// Pass A: per-block partial reduction over 8 j-rows, atomic-free.
// m[j,d]=max_b K; w=exp(K-m); partial num/den summed over the block's j's.
// 256 blocks (1/CU). Thread-half h covers j in [blk*8+h*4, +4), 8 d each.
// Halves merge via LDS [idx][dt] (conflict-free), half 0 stores partials:
// part[blk][0:4096]=num(b,d), part[blk][4096:8192]=den(b,d).
// ---------------------------------------------------------------------------
__global__ __launch_bounds__(256) void reduce_kv(
    const bf16* __restrict__ Kb, const bf16* __restrict__ Vb,
    float* __restrict__ part) {
  __shared__ float lds[64 * 128];
  const int t = threadIdx.x;
  const int half = t >> 7;
  const int dt = t & 127;
  const int d = dt * 8;
  const int j0 = blockIdx.x * 8 + half * 4;
  const size_t bs = (size_t)T_ * DH_;
  float n[4][8] = {}, e[4][8] = {};
  for (int jj = j0; jj < j0 + 4; ++jj) {
    size_t off = (size_t)jj * DH_ + d;
    bf16x8 kk[4], vv[4];
#pragma unroll
    for (int b = 0; b < 4; ++b) {
      kk[b] = *(const bf16x8*)(Kb + off + b * bs);
      vv[b] = *(const bf16x8*)(Vb + off + b * bs);
    }
#pragma unroll
    for (int c = 0; c < 8; ++c) {
      float k0 = (float)kk[0][c], k1 = (float)kk[1][c];
      float k2 = (float)kk[2][c], k3 = (float)kk[3][c];
      float m = fmaxf(fmaxf(k0, k1), fmaxf(k2, k3));
      float w0 = __expf(k0 - m), w1 = __expf(k1 - m);
      float w2 = __expf(k2 - m), w3 = __expf(k3 - m);
      e[0][c] += w0; e[1][c] += w1; e[2][c] += w2; e[3][c] += w3;
      n[0][c] += w0 * (float)vv[0][c];
      n[1][c] += w1 * (float)vv[1][c];
      n[2][c] += w2 * (float)vv[2][c];
      n[3][c] += w3 * (float)vv[3][c];
    }
  }
  if (half) {
#pragma unroll
    for (int b = 0; b < 4; ++b)
#pragma unroll
      for (int c = 0; c < 8; ++c) {
        lds[(b * 8 + c) * 128 + dt] = n[b][c];
        lds[(32 + b * 8 + c) * 128 + dt] = e[b][c];
      }
  }
  __syncthreads();
  if (!half) {
    float* po = part + (size_t)blockIdx.x * 8192;
#pragma unroll
    for (int b = 0; b < 4; ++b)
#pragma unroll
      for (int c = 0; c < 8; ++c) {
        po[b * 1024 + d + c] = n[b][c] + lds[(b * 8 + c) * 128 + dt];
        po[4096 + b * 1024 + d + c] = e[b][c] + lds[(32 + b * 8 + c) * 128 + dt];
      }
  }
}

// ---------------------------------------------------------------------------
// Pass B: numden[slot] = sum over 256 blocks of part[i][slot].
// 64 blocks x 256 threads; thread-half sums 128 partials (unroll-8 ILP),
// halves merge via LDS. Coalesced: consecutive threads = consecutive slots.
// ---------------------------------------------------------------------------
__global__ __launch_bounds__(256) void finish_kv(
    const float* __restrict__ part, float* __restrict__ numden) {
  __shared__ float lds[128];
  const int t = threadIdx.x;
  const int half = t >> 7;
  const int sl = t & 127;
  const int slot = blockIdx.x * 128 + sl;
  float s = 0.f;
  for (int i = half * 128; i < half * 128 + 128; i += 8) {
#pragma unroll
    for (int u = 0; u < 8; ++u)
      s += part[(size_t)(i + u) * 8192 + slot];
  }
  if (half) lds[sl] = s;
  __syncthreads();
  if (!half) numden[slot] = s + lds[sl];
}

// ---------------------------------------------------------------------------
// Yb[i] *= num[b,h]/den[b,h]  (in place, bf16).
// ---------------------------------------------------------------------------
__global__ __launch_bounds__(256) void mul_ratio(
    bf16* __restrict__ Yb, const float* __restrict__ num,
    const float* __restrict__ den) {
  size_t i = ((size_t)blockIdx.x * 256 + threadIdx.x) * 8;
  int h = (int)(i & (DH_ - 1));
  int b = (int)(i >> 21);
  bf16x8 y = *(bf16x8*)(Yb + i);
  const float* nu = num + b * DH_ + h;
  const float* de = den + b * DH_ + h;
  float4 n0 = *(const float4*)nu;
  float4 n1 = *(const float4*)(nu + 4);
  float4 d0 = *(const float4*)de;
  float4 d1 = *(const float4*)(de + 4);
  bf16x8 o;
  o[0] = (bf16)((float)y[0] * n0.x / d0.x);
  o[1] = (bf16)((float)y[1] * n0.y / d0.y);
  o[2] = (bf16)((float)y[2] * n0.z / d0.z);
  o[3] = (bf16)((float)y[3] * n0.w / d0.w);
  o[4] = (bf16)((float)y[4] * n1.x / d1.x);
  o[5] = (bf16)((float)y[5] * n1.y / d1.y);
  o[6] = (bf16)((float)y[6] * n1.z / d1.z);
  o[7] = (bf16)((float)y[7] * n1.w / d1.w);
  *(bf16x8*)(Yb + i) = o;
}

// ---------------------------------------------------------------------------
extern "C" void kernel_launch(void* const* d_in, const int* in_sizes, int n_in,
                              void* d_out, int out_size, void* d_ws, size_t ws_size,
                              hipStream_t stream) {
  const float* q  = (const float*)d_in[0];
  const float* k  = (const float*)d_in[1];
  const float* v  = (const float*)d_in[2];
  const float* Wq = (const float*)d_in[3];
  const float* Wk = (const float*)d_in[4];
  const float* Wv = (const float*)d_in[5];
  const float* Wo = (const float*)d_in[6];
  // d_in[7] = W_bias mathematically unused (exp_pos_bias == all-ones).
  float* out = (float*)d_out;

  char* ws = (char*)d_ws;
  size_t off = 0;
  auto alloc = [&](size_t bytes) {
    char* p = ws + off;
    off += (bytes + 255) & ~(size_t)255;
    return p;
  };
  const size_t actN = (size_t)MROWS * DM_;   // 8388608
  const size_t wN   = (size_t)DH_ * DM_;     // 1048576

  bf16* qb  = (bf16*)alloc(actN * 2);
  bf16* kb  = (bf16*)alloc(actN * 2);
  bf16* vb  = (bf16*)alloc(actN * 2);
  bf16* Wqb = (bf16*)alloc(wN * 2);
  bf16* Wkb = (bf16*)alloc(wN * 2);
  bf16* Wvb = (bf16*)alloc(wN * 2);
  bf16* Wob = (bf16*)alloc(wN * 2);
  bf16* Kb  = (bf16*)alloc(actN * 2);
  bf16* Vb  = (bf16*)alloc(actN * 2);
  bf16* Yb  = (bf16*)alloc(actN * 2);
  float* part = (float*)alloc((size_t)256 * 8192 * 4);   // 8 MB partials
  float* numden = (float*)alloc(8192 * 4);
  float* num = numden;
  float* den = numden + 4096;

  // 1) fp32 -> bf16 (activations + all 4 weights)
  CvtArgs ca;
  ca.job[0] = {q,  qb,  (int)(actN / 4)};
  ca.job[1] = {k,  kb,  (int)(actN / 4)};
  ca.job[2] = {v,  vb,  (int)(actN / 4)};
  ca.job[3] = {Wq, Wqb, (int)(wN / 4)};
  ca.job[4] = {Wk, Wkb, (int)(wN / 4)};
  ca.job[5] = {Wv, Wvb, (int)(wN / 4)};
  ca.job[6] = {Wo, Wob, (int)(wN / 4)};
  cvt_kernel<<<dim3(actN / 4 / 2048, 7), 256, 0, stream>>>(ca);

  // 2) merged K/V/Q projections (async bf16 staging; Q epilogue = sigmoid)
  GemmArgs g1;
  g1.N = DH_; g1.K = DM_;
  g1.job[0] = {kb, Wkb, nullptr, Kb, 2};
  g1.job[1] = {vb, Wvb, nullptr, Vb, 2};
  g1.job[2] = {qb, Wqb, nullptr, Yb, 1};
  g1.job[3] = {nullptr, nullptr, nullptr, nullptr, 0};
  gemm_bt<<<dim3(8, MROWS / 128, 3), 256, 0, stream>>>(g1);

  // 3) two-pass atomic-free reduction
  reduce_kv<<<dim3(256), 256, 0, stream>>>(Kb, Vb, part);
  finish_kv<<<dim3(64), 256, 0, stream>>>(part, numden);

  // 4) fold ratio into Y (in place)
  mul_ratio<<<dim3(actN / 8 / 256), 256, 0, stream>>>(Yb, num, den);

  // 5) out = Y' @ Wo^T  (single job, B shared across batches)
  GemmArgs g2;
  g2.N = DM_; g2.K = DH_;
  g2.job[0] = {Yb, Wob, out, nullptr, 0};
  g2.job[1] = g2.job[2] = g2.job[3] = {nullptr, nullptr, nullptr, nullptr, 0};
  gemm_bt<<<dim3(8, MROWS / 128, 1), 256, 0, stream>>>(g2);
}